// Round 3
// baseline (329.663 us; speedup 1.0000x reference)
//
#include <hip/hip_runtime.h>
#include <math.h>

#define B 4
#define C 64
#define H 256
#define W 256
#define CMID 16
#define CIN 73        // 64 + 9
#define HW (H*W)
#define NW (CIN*9*CMID)   // 10512 conv1 weights
#define XS_STRIDE 260     // offset kernel LDS row stride
#define XSR 258           // sim/conv1 LDS row stride: [0]=left halo,[1..256]=x,[257]=right

// ---------------------------------------------------------------------------
// w1 (CMID, CIN, 3, 3) -> wt[(ci*9+k)*CMID + co]
// ---------------------------------------------------------------------------
__global__ void transpose_w1_kernel(const float* __restrict__ w1, float* __restrict__ wt) {
    int tid = blockIdx.x * blockDim.x + threadIdx.x;
    if (tid >= NW) return;
    int co = tid & (CMID - 1);
    int rest = tid >> 4;          // ci*9 + k
    int ci = rest / 9;
    int k = rest - ci * 9;
    wt[tid] = w1[(co * CIN + ci) * 9 + k];
}

// 3x3 patch, row stride XSR. base = &xs[ch][tid].
__device__ __forceinline__ void read_patch9(const float* __restrict__ base, float v[9]) {
#pragma unroll
    for (int r = 0; r < 3; ++r) {
        v[r * 3 + 0] = base[r * XSR + 0];
        v[r * 3 + 1] = base[r * XSR + 1];
        v[r * 3 + 2] = base[r * XSR + 2];
    }
}

// ---------------------------------------------------------------------------
// Local cosine similarity. 1 px/thread, 4 ch per barrier, double-buffered.
// XCD-swizzled blocks. (unchanged from round 2 — carries the swizzle win)
// ---------------------------------------------------------------------------
__global__ __launch_bounds__(256) void sim_kernel(const float* __restrict__ x,
                                                  float* __restrict__ sim) {
    __shared__ float xs[2][4][3 * XSR];   // 24768 B

    int bid = blockIdx.x;
    int sb = (bid & 7) * 128 + (bid >> 3);   // XCD-contiguous bands (1024 = 8*128)
    int b = sb >> 8;
    int y = sb & 255;
    int tid = threadIdx.x;

    const float* xb = x + (size_t)b * C * HW;

    bool rv[3];
    long off[3];
#pragma unroll
    for (int j = 0; j < 3; ++j) {
        int grow = y - 1 + j;
        rv[j] = (grow >= 0) && (grow < H);
        off[j] = (long)grow * W + tid;
    }

    if (tid < 48) {   // zero halo cols: 2 bufs x 4 ch x 3 rows x {0,257}
        int e = tid & 1;
        int r = (tid >> 1) % 3;
        int q = (tid >> 1) / 3;
        (&xs[0][0][0])[q * (3 * XSR) + r * XSR + (e ? 257 : 0)] = 0.f;
    }

    float dot[9], nsq[9];
    float csq = 0.f;
#pragma unroll
    for (int i = 0; i < 9; ++i) { dot[i] = nsq[i] = 0.f; }

    float p[12];
#pragma unroll
    for (int k = 0; k < 4; ++k)
#pragma unroll
        for (int j = 0; j < 3; ++j)
            p[k * 3 + j] = rv[j] ? xb[(size_t)k * HW + off[j]] : 0.f;

    int cur = 0;
#pragma unroll 1
    for (int cc = 0; cc < C; cc += 4) {
#pragma unroll
        for (int k = 0; k < 4; ++k)
#pragma unroll
            for (int j = 0; j < 3; ++j)
                xs[cur][k][j * XSR + 1 + tid] = p[k * 3 + j];
        __syncthreads();

        if (cc + 4 < C) {
#pragma unroll
            for (int k = 0; k < 4; ++k)
#pragma unroll
                for (int j = 0; j < 3; ++j)
                    p[k * 3 + j] = rv[j] ? xb[(size_t)(cc + 4 + k) * HW + off[j]] : 0.f;
        }

#pragma unroll
        for (int k = 0; k < 4; ++k) {
            float v[9];
            read_patch9(&xs[cur][k][tid], v);
            float cv = v[4];
            csq = fmaf(cv, cv, csq);
#pragma unroll
            for (int kk = 0; kk < 9; ++kk) {
                if (kk == 4) continue;
                dot[kk] = fmaf(cv, v[kk], dot[kk]);
                nsq[kk] = fmaf(v[kk], v[kk], nsq[kk]);
            }
        }
        cur ^= 1;
    }

    dot[4] = csq;
    nsq[4] = csq;
    float cn = sqrtf(csq) + 1e-8f;
    float* so = sim + (size_t)b * 9 * HW + (size_t)y * W + tid;
#pragma unroll
    for (int kk = 0; kk < 9; ++kk)
        so[(size_t)kk * HW] = dot[kk] / (cn * (sqrtf(nsq[kk]) + 1e-8f));
}

// ---------------------------------------------------------------------------
// Conv1 (73->16) + leaky. 2 px/thread (vertical row pair).
// Weights: per-lane VMEM loads of wave-uniform addresses (forced off the
// scalar path via an opaque VGPR zero in the base pointer). VMEM is counted
// by vmcnt -> no lgkmcnt collisions with DS; compiler pipelines precisely.
// Per channel: 576 FMA-cyc vs 36 weight fetches (16 cyc/op budget).
// ---------------------------------------------------------------------------
__device__ __forceinline__ void conv1_ch_p2(const float* __restrict__ base,   // &xs[..][ch][tid]
                                            const float* __restrict__ wch,    // vgpr-forced global
                                            float acc0[CMID], float acc1[CMID]) {
    float v[4][3];
#pragma unroll
    for (int r = 0; r < 4; ++r) {
        v[r][0] = base[r * XSR + 0];
        v[r][1] = base[r * XSR + 1];
        v[r][2] = base[r * XSR + 2];
    }
#pragma unroll
    for (int kr = 0; kr < 3; ++kr)
#pragma unroll
        for (int kc = 0; kc < 3; ++kc) {
            const float4* w4 = (const float4*)(wch + (kr * 3 + kc) * CMID);
            float4 w0 = w4[0], w1 = w4[1], w2 = w4[2], w3 = w4[3];
            float a0 = v[kr][kc];       // output row y0   uses input rows kr
            float a1 = v[kr + 1][kc];   // output row y0+1 uses input rows kr+1
            acc0[0]  = fmaf(a0, w0.x, acc0[0]);  acc1[0]  = fmaf(a1, w0.x, acc1[0]);
            acc0[1]  = fmaf(a0, w0.y, acc0[1]);  acc1[1]  = fmaf(a1, w0.y, acc1[1]);
            acc0[2]  = fmaf(a0, w0.z, acc0[2]);  acc1[2]  = fmaf(a1, w0.z, acc1[2]);
            acc0[3]  = fmaf(a0, w0.w, acc0[3]);  acc1[3]  = fmaf(a1, w0.w, acc1[3]);
            acc0[4]  = fmaf(a0, w1.x, acc0[4]);  acc1[4]  = fmaf(a1, w1.x, acc1[4]);
            acc0[5]  = fmaf(a0, w1.y, acc0[5]);  acc1[5]  = fmaf(a1, w1.y, acc1[5]);
            acc0[6]  = fmaf(a0, w1.z, acc0[6]);  acc1[6]  = fmaf(a1, w1.z, acc1[6]);
            acc0[7]  = fmaf(a0, w1.w, acc0[7]);  acc1[7]  = fmaf(a1, w1.w, acc1[7]);
            acc0[8]  = fmaf(a0, w2.x, acc0[8]);  acc1[8]  = fmaf(a1, w2.x, acc1[8]);
            acc0[9]  = fmaf(a0, w2.y, acc0[9]);  acc1[9]  = fmaf(a1, w2.y, acc1[9]);
            acc0[10] = fmaf(a0, w2.z, acc0[10]); acc1[10] = fmaf(a1, w2.z, acc1[10]);
            acc0[11] = fmaf(a0, w2.w, acc0[11]); acc1[11] = fmaf(a1, w2.w, acc1[11]);
            acc0[12] = fmaf(a0, w3.x, acc0[12]); acc1[12] = fmaf(a1, w3.x, acc1[12]);
            acc0[13] = fmaf(a0, w3.y, acc0[13]); acc1[13] = fmaf(a1, w3.y, acc1[13]);
            acc0[14] = fmaf(a0, w3.z, acc0[14]); acc1[14] = fmaf(a1, w3.z, acc1[14]);
            acc0[15] = fmaf(a0, w3.w, acc0[15]); acc1[15] = fmaf(a1, w3.w, acc1[15]);
        }
}

__global__ __launch_bounds__(256) void conv1_kernel(const float* __restrict__ x,
                                                    const float* __restrict__ sim,
                                                    const float* __restrict__ wt,
                                                    const float* __restrict__ b1,
                                                    float* __restrict__ h) {
    __shared__ float xs[2][2][4 * XSR];   // dbuf x 2ch x 4 rows = 16512 B

    int tid = threadIdx.x;
    int bid = blockIdx.x;
    int sb = (bid & 7) * 64 + (bid >> 3);    // XCD-contiguous bands (512 = 8*64)
    int b  = sb >> 7;
    int y0 = (sb & 127) << 1;                // row pair y0, y0+1

    // Opaque VGPR zero: prevents uniformity analysis from turning the
    // wave-uniform weight loads back into s_load (the r0/r1 lgkmcnt poison).
    int vz;
    asm volatile("v_mov_b32 %0, 0" : "=v"(vz));
    const float* wv = wt + vz;

    const float* gx = x + (size_t)b * C * HW;
    const float* gs = sim + (size_t)b * 9 * HW;

    bool rv[4];
    long off[4];
#pragma unroll
    for (int j = 0; j < 4; ++j) {
        int grow = y0 - 1 + j;
        rv[j] = (grow >= 0) && (grow < H);
        off[j] = (long)grow * W + tid;
    }

    if (tid < 32) {   // zero halo cols: 2 bufs x 2 ch x 4 rows x {0,257}
        int e = tid & 1;
        int r = (tid >> 1) & 3;
        int q = tid >> 3;                 // buf*2 + ch
        (&xs[0][0][0])[q * (4 * XSR) + r * XSR + (e ? 257 : 0)] = 0.f;
    }

    float acc0[CMID], acc1[CMID];
#pragma unroll
    for (int co = 0; co < CMID; ++co) { acc0[co] = b1[co]; acc1[co] = b1[co]; }

    // prefetch channels 0,1 (4 rows each)
    float p[8];
#pragma unroll
    for (int k = 0; k < 2; ++k)
#pragma unroll
        for (int j = 0; j < 4; ++j)
            p[k * 4 + j] = rv[j] ? gx[(size_t)k * HW + off[j]] : 0.f;

    int cur = 0;
#pragma unroll 1
    for (int cc = 0; cc < 72; cc += 2) {
#pragma unroll
        for (int k = 0; k < 2; ++k)
#pragma unroll
            for (int j = 0; j < 4; ++j)
                xs[cur][k][j * XSR + 1 + tid] = p[k * 4 + j];
        __syncthreads();

        // prefetch cc+2, cc+3 (uniform guards)
#pragma unroll
        for (int k = 0; k < 2; ++k) {
            int ci = cc + 2 + k;
            if (ci < CIN) {
                const float* cb = (ci < C) ? (gx + (size_t)ci * HW)
                                           : (gs + (size_t)(ci - C) * HW);
#pragma unroll
                for (int j = 0; j < 4; ++j)
                    p[k * 4 + j] = rv[j] ? cb[off[j]] : 0.f;
            }
        }

        conv1_ch_p2(&xs[cur][0][tid], wv + (size_t)cc * 144, acc0, acc1);
        conv1_ch_p2(&xs[cur][1][tid], wv + (size_t)(cc + 1) * 144, acc0, acc1);
        cur ^= 1;
    }

    // tail channel ci = 72 (prefetched into p[0..3] at cc=70)
#pragma unroll
    for (int j = 0; j < 4; ++j)
        xs[cur][0][j * XSR + 1 + tid] = p[j];
    __syncthreads();
    conv1_ch_p2(&xs[cur][0][tid], wv + (size_t)72 * 144, acc0, acc1);

    float* ho = h + (size_t)b * CMID * HW + (size_t)y0 * W + tid;
#pragma unroll
    for (int co = 0; co < CMID; ++co) {
        float v0 = acc0[co], v1 = acc1[co];
        v0 = v0 >= 0.f ? v0 : 0.2f * v0;
        v1 = v1 >= 0.f ? v1 : 0.2f * v1;
        ho[(size_t)co * HW]     = v0;
        ho[(size_t)co * HW + W] = v1;
    }
}

// ---------------------------------------------------------------------------
// Strip helpers for offset kernel (2-px/thread structure, stride 260).
// ---------------------------------------------------------------------------
__device__ __forceinline__ void read_patch_lds(const float* __restrict__ xsbuf,
                                               int rl, int px, float v[3][4]) {
    const float* pb = xsbuf + rl * XS_STRIDE + px;
#pragma unroll
    for (int r = 0; r < 3; ++r) {
        float2 p0 = *(const float2*)(pb + r * XS_STRIDE);
        float2 p1 = *(const float2*)(pb + r * XS_STRIDE + 2);
        v[r][0] = p0.x; v[r][1] = p0.y; v[r][2] = p1.x; v[r][3] = p1.y;
    }
}

// ---------------------------------------------------------------------------
// Conv2 (16->2) + tanh -> clamped sample coords. (unchanged from round 2)
// ---------------------------------------------------------------------------
__global__ __launch_bounds__(256) void offset_kernel(const float* __restrict__ h,
                                                     const float* __restrict__ w2,
                                                     const float* __restrict__ b2,
                                                     float2* __restrict__ off_buf) {
    __shared__ float lw2[CMID * 9 * 2];
    __shared__ float xs[2][4 * XS_STRIDE];

    int tid = threadIdx.x;
    for (int i = tid; i < CMID * 9 * 2; i += 256) {
        int co = i & 1;
        int rest = i >> 1;
        int ci = rest / 9;
        int kk = rest - ci * 9;
        lw2[i] = w2[(co * CMID + ci) * 9 + kk];
    }

    int bid = blockIdx.x;
    int sb = (bid & 7) * 64 + (bid >> 3);    // XCD-contiguous bands (512 = 8*64)
    int b  = sb >> 7;
    int y0 = (sb & 127) << 1;
    int srow = tid >> 6;
    int sx4  = (tid & 63) << 2;
    int rl = tid >> 7;
    int px = (tid & 127) << 1;
    int y  = y0 + rl;

    int grow = y0 - 1 + srow;
    bool gvalid = (grow >= 0) && (grow < H);
    const float* gh = h + (size_t)b * CMID * HW + (size_t)grow * W + sx4;

    if (tid < 16) {
        int bu = tid >> 3, r = (tid >> 1) & 3, e = (tid & 1) ? 257 : 0;
        xs[bu][r * XS_STRIDE + e] = 0.f;
    }

    float s0x = b2[0], s0y = b2[1], s1x = b2[0], s1y = b2[1];

    float4 r4 = make_float4(0.f, 0.f, 0.f, 0.f);
    if (gvalid) r4 = *(const float4*)gh;

    int cur = 0;
#pragma unroll 1
    for (int ci = 0; ci < CMID; ++ci) {
        float* dst = &xs[cur][srow * XS_STRIDE + 1 + sx4];
        dst[0] = r4.x; dst[1] = r4.y; dst[2] = r4.z; dst[3] = r4.w;
        __syncthreads();
        if (ci + 1 < CMID) {
            r4 = make_float4(0.f, 0.f, 0.f, 0.f);
            if (gvalid) r4 = *(const float4*)(gh + (size_t)(ci + 1) * HW);
        }
        float v[3][4];
        read_patch_lds(xs[cur], rl, px, v);
#pragma unroll
        for (int kr = 0; kr < 3; ++kr)
#pragma unroll
            for (int kc = 0; kc < 3; ++kc) {
                float2 wv = *(const float2*)(lw2 + (ci * 9 + kr * 3 + kc) * 2);
                s0x = fmaf(v[kr][kc],     wv.x, s0x);
                s0y = fmaf(v[kr][kc],     wv.y, s0y);
                s1x = fmaf(v[kr][kc + 1], wv.x, s1x);
                s1y = fmaf(v[kr][kc + 1], wv.y, s1y);
            }
        cur ^= 1;
    }

    float ix0 = (float)px       + 0.1f * tanhf(s0x) * (0.5f * (float)(W - 1));
    float iy0 = (float)y        + 0.1f * tanhf(s0y) * (0.5f * (float)(H - 1));
    float ix1 = (float)(px + 1) + 0.1f * tanhf(s1x) * (0.5f * (float)(W - 1));
    float iy1 = (float)y        + 0.1f * tanhf(s1y) * (0.5f * (float)(H - 1));
    ix0 = fminf(fmaxf(ix0, 0.f), (float)(W - 1));
    iy0 = fminf(fmaxf(iy0, 0.f), (float)(H - 1));
    ix1 = fminf(fmaxf(ix1, 0.f), (float)(W - 1));
    iy1 = fminf(fmaxf(iy1, 0.f), (float)(H - 1));

    float4* op = (float4*)(off_buf + (size_t)b * HW + (size_t)y * W + px);
    *op = make_float4(ix0, iy0, ix1, iy1);
}

// ---------------------------------------------------------------------------
// Bilinear border sample via LDS row cache. (unchanged)
// ---------------------------------------------------------------------------
#define SROWS 35
__global__ __launch_bounds__(256) void sample_kernel(const float* __restrict__ x,
                                                     const float2* __restrict__ off_buf,
                                                     float* __restrict__ out) {
    __shared__ float xs[SROWS * 256];    // 35840 B

    int bid = blockIdx.x;                        // 0..127 tiles
    int sb = (bid & 7) * 16 + (bid >> 3);        // XCD-contiguous 16-tile bands
    int b  = sb >> 5;
    int ty = sb & 31;
    int cg = blockIdx.y;                         // 0..15 channel groups (4 ch)
    int tid = threadIdx.x;                       // column

    int ybase = ty << 3;
    int lo = ybase - 13;

    int a00[8], a01[8], a10[8], a11[8];
    float wx[8], wy[8];
    const float2* ob2 = off_buf + (size_t)b * HW + (size_t)ybase * W + tid;
#pragma unroll
    for (int r = 0; r < 8; ++r) {
        float2 o = ob2[r * W];
        float xf = floorf(o.x), yf = floorf(o.y);
        wx[r] = o.x - xf; wy[r] = o.y - yf;
        int x0 = (int)xf, yy0 = (int)yf;
        int x1 = min(x0 + 1, W - 1), yy1 = min(yy0 + 1, H - 1);
        int r0 = (yy0 - lo) << 8, r1 = (yy1 - lo) << 8;
        a00[r] = r0 + x0; a01[r] = r0 + x1;
        a10[r] = r1 + x0; a11[r] = r1 + x1;
    }

    const float* xb = x + ((size_t)b * C + cg * 4) * HW;
    float* outb = out + ((size_t)b * C + cg * 4) * HW + (size_t)ybase * W + tid;

#pragma unroll 1
    for (int c = 0; c < 4; ++c) {
        __syncthreads();
        const float* src = xb + (size_t)c * HW;
        for (int j = tid; j < SROWS * 64; j += 256) {
            int row = j >> 6, x4 = (j & 63) << 2;
            int grw = min(max(lo + row, 0), H - 1);
            *(float4*)&xs[(row << 8) + x4] = *(const float4*)(src + (size_t)grw * W + x4);
        }
        __syncthreads();
        float* oc = outb + (size_t)c * HW;
#pragma unroll
        for (int r = 0; r < 8; ++r) {
            float v00 = xs[a00[r]], v01 = xs[a01[r]];
            float v10 = xs[a10[r]], v11 = xs[a11[r]];
            float top = fmaf(wx[r], v01 - v00, v00);
            float bot = fmaf(wx[r], v11 - v10, v10);
            oc[r * W] = fmaf(wy[r], bot - top, top);
        }
    }
}

// ---------------------------------------------------------------------------
extern "C" void kernel_launch(void* const* d_in, const int* in_sizes, int n_in,
                              void* d_out, int out_size, void* d_ws, size_t ws_size,
                              hipStream_t stream) {
    const float* x  = (const float*)d_in[0];
    const float* w1 = (const float*)d_in[1];
    const float* b1 = (const float*)d_in[2];
    const float* w2 = (const float*)d_in[3];
    const float* b2 = (const float*)d_in[4];
    float* out = (float*)d_out;

    float* ws  = (float*)d_ws;
    float* wt  = ws;                                         // 16384 floats
    float* sim = ws + 16384;                                 // B*9*HW
    float* h   = sim + (size_t)B * 9 * HW;                   // B*16*HW
    float2* off_buf = (float2*)(h + (size_t)B * CMID * HW);  // B*HW float2

    transpose_w1_kernel<<<(NW + 255) / 256, 256, 0, stream>>>(w1, wt);

    sim_kernel<<<B * H, 256, 0, stream>>>(x, sim);
    conv1_kernel<<<512, 256, 0, stream>>>(x, sim, wt, b1, h);
    offset_kernel<<<512, 256, 0, stream>>>(h, w2, b2, off_buf);
    sample_kernel<<<dim3(128, 16), 256, 0, stream>>>(x, off_buf, out);
}

// Round 4
// 241.657 us; speedup vs baseline: 1.3642x; 1.3642x over previous
//
#include <hip/hip_runtime.h>
#include <math.h>

#define B 4
#define C 64
#define H 256
#define W 256
#define CMID 16
#define CIN 73        // 64 + 9
#define HW (H*W)
#define NW (CIN*9*CMID)   // 10512 conv1 weights
#define XS_STRIDE 260     // offset kernel LDS row stride
#define XSR 258           // sim LDS row stride: [0]=left halo,[1..256]=x,[257]=right
#define XSW 256           // conv1 LDS row stride (no halo slots; edges via DPP)

// ---------------------------------------------------------------------------
// w1 (CMID, CIN, 3, 3) -> wt[(ci*9+k)*CMID + co]
// ---------------------------------------------------------------------------
__global__ void transpose_w1_kernel(const float* __restrict__ w1, float* __restrict__ wt) {
    int tid = blockIdx.x * blockDim.x + threadIdx.x;
    if (tid >= NW) return;
    int co = tid & (CMID - 1);
    int rest = tid >> 4;          // ci*9 + k
    int ci = rest / 9;
    int k = rest - ci * 9;
    wt[tid] = w1[(co * CIN + ci) * 9 + k];
}

// 3x3 patch, row stride XSR. base = &xs[ch][tid]. (sim kernel)
__device__ __forceinline__ void read_patch9(const float* __restrict__ base, float v[9]) {
#pragma unroll
    for (int r = 0; r < 3; ++r) {
        v[r * 3 + 0] = base[r * XSR + 0];
        v[r * 3 + 1] = base[r * XSR + 1];
        v[r * 3 + 2] = base[r * XSR + 2];
    }
}

// ---------------------------------------------------------------------------
// Local cosine similarity. 1 px/thread, 4 ch per barrier, double-buffered.
// XCD-swizzled blocks. (unchanged — carries the swizzle win)
// ---------------------------------------------------------------------------
__global__ __launch_bounds__(256) void sim_kernel(const float* __restrict__ x,
                                                  float* __restrict__ sim) {
    __shared__ float xs[2][4][3 * XSR];   // 24768 B

    int bid = blockIdx.x;
    int sb = (bid & 7) * 128 + (bid >> 3);   // XCD-contiguous bands (1024 = 8*128)
    int b = sb >> 8;
    int y = sb & 255;
    int tid = threadIdx.x;

    const float* xb = x + (size_t)b * C * HW;

    bool rv[3];
    long off[3];
#pragma unroll
    for (int j = 0; j < 3; ++j) {
        int grow = y - 1 + j;
        rv[j] = (grow >= 0) && (grow < H);
        off[j] = (long)grow * W + tid;
    }

    if (tid < 48) {   // zero halo cols: 2 bufs x 4 ch x 3 rows x {0,257}
        int e = tid & 1;
        int r = (tid >> 1) % 3;
        int q = (tid >> 1) / 3;
        (&xs[0][0][0])[q * (3 * XSR) + r * XSR + (e ? 257 : 0)] = 0.f;
    }

    float dot[9], nsq[9];
    float csq = 0.f;
#pragma unroll
    for (int i = 0; i < 9; ++i) { dot[i] = nsq[i] = 0.f; }

    float p[12];
#pragma unroll
    for (int k = 0; k < 4; ++k)
#pragma unroll
        for (int j = 0; j < 3; ++j)
            p[k * 3 + j] = rv[j] ? xb[(size_t)k * HW + off[j]] : 0.f;

    int cur = 0;
#pragma unroll 1
    for (int cc = 0; cc < C; cc += 4) {
#pragma unroll
        for (int k = 0; k < 4; ++k)
#pragma unroll
            for (int j = 0; j < 3; ++j)
                xs[cur][k][j * XSR + 1 + tid] = p[k * 3 + j];
        __syncthreads();

        if (cc + 4 < C) {
#pragma unroll
            for (int k = 0; k < 4; ++k)
#pragma unroll
                for (int j = 0; j < 3; ++j)
                    p[k * 3 + j] = rv[j] ? xb[(size_t)(cc + 4 + k) * HW + off[j]] : 0.f;
        }

#pragma unroll
        for (int k = 0; k < 4; ++k) {
            float v[9];
            read_patch9(&xs[cur][k][tid], v);
            float cv = v[4];
            csq = fmaf(cv, cv, csq);
#pragma unroll
            for (int kk = 0; kk < 9; ++kk) {
                if (kk == 4) continue;
                dot[kk] = fmaf(cv, v[kk], dot[kk]);
                nsq[kk] = fmaf(v[kk], v[kk], nsq[kk]);
            }
        }
        cur ^= 1;
    }

    dot[4] = csq;
    nsq[4] = csq;
    float cn = sqrtf(csq) + 1e-8f;
    float* so = sim + (size_t)b * 9 * HW + (size_t)y * W + tid;
#pragma unroll
    for (int kk = 0; kk < 9; ++kk)
        so[(size_t)kk * HW] = dot[kk] / (cn * (sqrtf(nsq[kk]) + 1e-8f));
}

// ---------------------------------------------------------------------------
// Conv1 (73->16) + leaky.  co-split x 8px/thread design:
//   block = 2 rows x 256 cols, 4 waves; wave w computes co 4w..4w+3 for all px.
//   Thread (lane l): 2 rows x 4 cols (cols 4l..4l+3).
//   Patch: 1 aligned ds_read_b128 per staged row; +-1 col halo via DPP
//     wave_shr/wave_shl (VALU pipe, bound_ctrl -> image-pad zero for free).
//   Weights: 9 float4/ci per wave, VGPR double-buffered, prefetched one FULL
//     channel (~576 FMA-cyc) ahead via forced-VMEM loads (vmcnt, not lgkmcnt).
//   Inner loop has NO SMEM and minimal DS -> precise lgkmcnt, no drains.
// ---------------------------------------------------------------------------
__device__ __forceinline__ float dpp_shr1(float x) {   // lane i <- lane i-1 (lane0 -> 0)
    return __int_as_float(__builtin_amdgcn_update_dpp(
        0, __float_as_int(x), 0x138, 0xf, 0xf, false));
}
__device__ __forceinline__ float dpp_shl1(float x) {   // lane i <- lane i+1 (lane63 -> 0)
    return __int_as_float(__builtin_amdgcn_update_dpp(
        0, __float_as_int(x), 0x130, 0xf, 0xf, false));
}

__device__ __forceinline__ void conv1_co4(const float* __restrict__ chbase, int l,
                                          const float4 wv[9], float4 acc[2][4]) {
    float v[4][6];
#pragma unroll
    for (int r = 0; r < 4; ++r) {
        const float* rp = chbase + r * XSW;
        float4 m = *(const float4*)(rp + 4 * l);
        v[r][1] = m.x; v[r][2] = m.y; v[r][3] = m.z; v[r][4] = m.w;
        v[r][0] = dpp_shr1(m.w);   // col 4l-1 (lane0: col -1 = pad 0)
        v[r][5] = dpp_shl1(m.x);   // col 4l+4 (lane63: col 256 = pad 0)
    }
#pragma unroll
    for (int kr = 0; kr < 3; ++kr)
#pragma unroll
        for (int kc = 0; kc < 3; ++kc) {
            float4 w = wv[kr * 3 + kc];
#pragma unroll
            for (int rr = 0; rr < 2; ++rr)
#pragma unroll
                for (int cc = 0; cc < 4; ++cc) {
                    float a = v[rr + kr][cc + kc];
                    acc[rr][cc].x = fmaf(a, w.x, acc[rr][cc].x);
                    acc[rr][cc].y = fmaf(a, w.y, acc[rr][cc].y);
                    acc[rr][cc].z = fmaf(a, w.z, acc[rr][cc].z);
                    acc[rr][cc].w = fmaf(a, w.w, acc[rr][cc].w);
                }
        }
}

__global__ __launch_bounds__(256) void conv1_kernel(const float* __restrict__ x,
                                                    const float* __restrict__ sim,
                                                    const float* __restrict__ wt,
                                                    const float* __restrict__ b1,
                                                    float* __restrict__ h) {
    __shared__ __align__(16) float xs[2][2][4 * XSW];   // 2 buf x 2 ch x 4 rows = 16384 B

    int tid = threadIdx.x;
    int l = tid & 63;
    int wid = tid >> 6;                       // wave: stages row wid, computes co 4*wid..+3
    int bid = blockIdx.x;
    int sb = (bid & 7) * 64 + (bid >> 3);     // XCD-contiguous bands (512 = 8*64)
    int b  = sb >> 7;
    int y0 = (sb & 127) << 1;

    // Opaque VGPR zero: keeps the wave-uniform weight loads on the VMEM path
    // (vmcnt), not the scalar path (lgkmcnt — the r0/r1 drain poison).
    int vz;
    asm volatile("v_mov_b32 %0, 0" : "=v"(vz));
    const float4* wq = (const float4*)wt + vz;

    const float* gx = x + (size_t)b * C * HW;
    const float* gs = sim + (size_t)b * 9 * HW;

    int grow = y0 - 1 + wid;                  // wave-uniform staging row
    bool rvw = (grow >= 0) && (grow < H);
    size_t goff = (size_t)grow * W + 4 * l;

    float4 bias = ((const float4*)b1)[wid];
    float4 acc[2][4];
#pragma unroll
    for (int rr = 0; rr < 2; ++rr)
#pragma unroll
        for (int cc = 0; cc < 4; ++cc) acc[rr][cc] = bias;

    float4 wA[9], wB[9];
#pragma unroll
    for (int k = 0; k < 9; ++k) wA[k] = wq[k * 4 + wid];   // weights ch 0

    float4 p0 = make_float4(0.f, 0.f, 0.f, 0.f), p1 = p0;
    if (rvw) {
        p0 = *(const float4*)(gx + goff);
        p1 = *(const float4*)(gx + HW + goff);
    }

    int cur = 0;
#pragma unroll 1
    for (int cc2 = 0; cc2 < 72; cc2 += 2) {
        *(float4*)&xs[cur][0][wid * XSW + 4 * l] = p0;
        *(float4*)&xs[cur][1][wid * XSW + 4 * l] = p1;
        __syncthreads();

        // prefetch activations cc2+2, cc2+3 (uniform guards)
        {
            int ci = cc2 + 2;
            p0 = make_float4(0.f, 0.f, 0.f, 0.f);
            if (rvw)
                p0 = (ci < C) ? *(const float4*)(gx + (size_t)ci * HW + goff)
                              : *(const float4*)(gs + (size_t)(ci - C) * HW + goff);
            int cj = cc2 + 3;
            p1 = make_float4(0.f, 0.f, 0.f, 0.f);
            if (rvw && cj < CIN)
                p1 = (cj < C) ? *(const float4*)(gx + (size_t)cj * HW + goff)
                              : *(const float4*)(gs + (size_t)(cj - C) * HW + goff);
        }

        // prefetch weights ch cc2+1 (consumed one channel later)
#pragma unroll
        for (int k = 0; k < 9; ++k) wB[k] = wq[((cc2 + 1) * 9 + k) * 4 + wid];

        conv1_co4(&xs[cur][0][0], l, wA, acc);      // ch cc2

        // prefetch weights ch cc2+2
#pragma unroll
        for (int k = 0; k < 9; ++k) wA[k] = wq[((cc2 + 2) * 9 + k) * 4 + wid];

        conv1_co4(&xs[cur][1][0], l, wB, acc);      // ch cc2+1

        cur ^= 1;
    }

    // tail ci = 72 (activations in p0, weights in wA — both prefetched at cc2=70)
    *(float4*)&xs[cur][0][wid * XSW + 4 * l] = p0;
    __syncthreads();
    conv1_co4(&xs[cur][0][0], l, wA, acc);

    // epilogue: leaky, transpose acc (col-vector-of-co -> co-planes), float4 stores
    float* ho = h + ((size_t)b * CMID + 4 * wid) * HW + (size_t)y0 * W + 4 * l;
#pragma unroll
    for (int rr = 0; rr < 2; ++rr)
#pragma unroll
        for (int j = 0; j < 4; ++j) {
            float4 o;
            o.x = ((const float*)&acc[rr][0])[j];
            o.y = ((const float*)&acc[rr][1])[j];
            o.z = ((const float*)&acc[rr][2])[j];
            o.w = ((const float*)&acc[rr][3])[j];
            o.x = o.x >= 0.f ? o.x : 0.2f * o.x;
            o.y = o.y >= 0.f ? o.y : 0.2f * o.y;
            o.z = o.z >= 0.f ? o.z : 0.2f * o.z;
            o.w = o.w >= 0.f ? o.w : 0.2f * o.w;
            *(float4*)(ho + (size_t)j * HW + (size_t)rr * W) = o;
        }
}

// ---------------------------------------------------------------------------
// Strip helpers for offset kernel (2-px/thread structure, stride 260).
// ---------------------------------------------------------------------------
__device__ __forceinline__ void read_patch_lds(const float* __restrict__ xsbuf,
                                               int rl, int px, float v[3][4]) {
    const float* pb = xsbuf + rl * XS_STRIDE + px;
#pragma unroll
    for (int r = 0; r < 3; ++r) {
        float2 p0 = *(const float2*)(pb + r * XS_STRIDE);
        float2 p1 = *(const float2*)(pb + r * XS_STRIDE + 2);
        v[r][0] = p0.x; v[r][1] = p0.y; v[r][2] = p1.x; v[r][3] = p1.y;
    }
}

// ---------------------------------------------------------------------------
// Conv2 (16->2) + tanh -> clamped sample coords. (unchanged)
// ---------------------------------------------------------------------------
__global__ __launch_bounds__(256) void offset_kernel(const float* __restrict__ h,
                                                     const float* __restrict__ w2,
                                                     const float* __restrict__ b2,
                                                     float2* __restrict__ off_buf) {
    __shared__ float lw2[CMID * 9 * 2];
    __shared__ float xs[2][4 * XS_STRIDE];

    int tid = threadIdx.x;
    for (int i = tid; i < CMID * 9 * 2; i += 256) {
        int co = i & 1;
        int rest = i >> 1;
        int ci = rest / 9;
        int kk = rest - ci * 9;
        lw2[i] = w2[(co * CMID + ci) * 9 + kk];
    }

    int bid = blockIdx.x;
    int sb = (bid & 7) * 64 + (bid >> 3);    // XCD-contiguous bands (512 = 8*64)
    int b  = sb >> 7;
    int y0 = (sb & 127) << 1;
    int srow = tid >> 6;
    int sx4  = (tid & 63) << 2;
    int rl = tid >> 7;
    int px = (tid & 127) << 1;
    int y  = y0 + rl;

    int grow = y0 - 1 + srow;
    bool gvalid = (grow >= 0) && (grow < H);
    const float* gh = h + (size_t)b * CMID * HW + (size_t)grow * W + sx4;

    if (tid < 16) {
        int bu = tid >> 3, r = (tid >> 1) & 3, e = (tid & 1) ? 257 : 0;
        xs[bu][r * XS_STRIDE + e] = 0.f;
    }

    float s0x = b2[0], s0y = b2[1], s1x = b2[0], s1y = b2[1];

    float4 r4 = make_float4(0.f, 0.f, 0.f, 0.f);
    if (gvalid) r4 = *(const float4*)gh;

    int cur = 0;
#pragma unroll 1
    for (int ci = 0; ci < CMID; ++ci) {
        float* dst = &xs[cur][srow * XS_STRIDE + 1 + sx4];
        dst[0] = r4.x; dst[1] = r4.y; dst[2] = r4.z; dst[3] = r4.w;
        __syncthreads();
        if (ci + 1 < CMID) {
            r4 = make_float4(0.f, 0.f, 0.f, 0.f);
            if (gvalid) r4 = *(const float4*)(gh + (size_t)(ci + 1) * HW);
        }
        float v[3][4];
        read_patch_lds(xs[cur], rl, px, v);
#pragma unroll
        for (int kr = 0; kr < 3; ++kr)
#pragma unroll
            for (int kc = 0; kc < 3; ++kc) {
                float2 wv = *(const float2*)(lw2 + (ci * 9 + kr * 3 + kc) * 2);
                s0x = fmaf(v[kr][kc],     wv.x, s0x);
                s0y = fmaf(v[kr][kc],     wv.y, s0y);
                s1x = fmaf(v[kr][kc + 1], wv.x, s1x);
                s1y = fmaf(v[kr][kc + 1], wv.y, s1y);
            }
        cur ^= 1;
    }

    float ix0 = (float)px       + 0.1f * tanhf(s0x) * (0.5f * (float)(W - 1));
    float iy0 = (float)y        + 0.1f * tanhf(s0y) * (0.5f * (float)(H - 1));
    float ix1 = (float)(px + 1) + 0.1f * tanhf(s1x) * (0.5f * (float)(W - 1));
    float iy1 = (float)y        + 0.1f * tanhf(s1y) * (0.5f * (float)(H - 1));
    ix0 = fminf(fmaxf(ix0, 0.f), (float)(W - 1));
    iy0 = fminf(fmaxf(iy0, 0.f), (float)(H - 1));
    ix1 = fminf(fmaxf(ix1, 0.f), (float)(W - 1));
    iy1 = fminf(fmaxf(iy1, 0.f), (float)(H - 1));

    float4* op = (float4*)(off_buf + (size_t)b * HW + (size_t)y * W + px);
    *op = make_float4(ix0, iy0, ix1, iy1);
}

// ---------------------------------------------------------------------------
// Bilinear border sample via LDS row cache. (unchanged)
// ---------------------------------------------------------------------------
#define SROWS 35
__global__ __launch_bounds__(256) void sample_kernel(const float* __restrict__ x,
                                                     const float2* __restrict__ off_buf,
                                                     float* __restrict__ out) {
    __shared__ float xs[SROWS * 256];    // 35840 B

    int bid = blockIdx.x;                        // 0..127 tiles
    int sb = (bid & 7) * 16 + (bid >> 3);        // XCD-contiguous 16-tile bands
    int b  = sb >> 5;
    int ty = sb & 31;
    int cg = blockIdx.y;                         // 0..15 channel groups (4 ch)
    int tid = threadIdx.x;                       // column

    int ybase = ty << 3;
    int lo = ybase - 13;

    int a00[8], a01[8], a10[8], a11[8];
    float wx[8], wy[8];
    const float2* ob2 = off_buf + (size_t)b * HW + (size_t)ybase * W + tid;
#pragma unroll
    for (int r = 0; r < 8; ++r) {
        float2 o = ob2[r * W];
        float xf = floorf(o.x), yf = floorf(o.y);
        wx[r] = o.x - xf; wy[r] = o.y - yf;
        int x0 = (int)xf, yy0 = (int)yf;
        int x1 = min(x0 + 1, W - 1), yy1 = min(yy0 + 1, H - 1);
        int r0 = (yy0 - lo) << 8, r1 = (yy1 - lo) << 8;
        a00[r] = r0 + x0; a01[r] = r0 + x1;
        a10[r] = r1 + x0; a11[r] = r1 + x1;
    }

    const float* xb = x + ((size_t)b * C + cg * 4) * HW;
    float* outb = out + ((size_t)b * C + cg * 4) * HW + (size_t)ybase * W + tid;

#pragma unroll 1
    for (int c = 0; c < 4; ++c) {
        __syncthreads();
        const float* src = xb + (size_t)c * HW;
        for (int j = tid; j < SROWS * 64; j += 256) {
            int row = j >> 6, x4 = (j & 63) << 2;
            int grw = min(max(lo + row, 0), H - 1);
            *(float4*)&xs[(row << 8) + x4] = *(const float4*)(src + (size_t)grw * W + x4);
        }
        __syncthreads();
        float* oc = outb + (size_t)c * HW;
#pragma unroll
        for (int r = 0; r < 8; ++r) {
            float v00 = xs[a00[r]], v01 = xs[a01[r]];
            float v10 = xs[a10[r]], v11 = xs[a11[r]];
            float top = fmaf(wx[r], v01 - v00, v00);
            float bot = fmaf(wx[r], v11 - v10, v10);
            oc[r * W] = fmaf(wy[r], bot - top, top);
        }
    }
}

// ---------------------------------------------------------------------------
extern "C" void kernel_launch(void* const* d_in, const int* in_sizes, int n_in,
                              void* d_out, int out_size, void* d_ws, size_t ws_size,
                              hipStream_t stream) {
    const float* x  = (const float*)d_in[0];
    const float* w1 = (const float*)d_in[1];
    const float* b1 = (const float*)d_in[2];
    const float* w2 = (const float*)d_in[3];
    const float* b2 = (const float*)d_in[4];
    float* out = (float*)d_out;

    float* ws  = (float*)d_ws;
    float* wt  = ws;                                         // 16384 floats
    float* sim = ws + 16384;                                 // B*9*HW
    float* h   = sim + (size_t)B * 9 * HW;                   // B*16*HW
    float2* off_buf = (float2*)(h + (size_t)B * CMID * HW);  // B*HW float2

    transpose_w1_kernel<<<(NW + 255) / 256, 256, 0, stream>>>(w1, wt);

    sim_kernel<<<B * H, 256, 0, stream>>>(x, sim);
    conv1_kernel<<<512, 256, 0, stream>>>(x, sim, wt, b1, h);
    offset_kernel<<<512, 256, 0, stream>>>(h, w2, b2, off_buf);
    sample_kernel<<<dim3(128, 16), 256, 0, stream>>>(x, off_buf, out);
}

// Round 5
// 238.793 us; speedup vs baseline: 1.3805x; 1.0120x over previous
//
#include <hip/hip_runtime.h>
#include <math.h>

#define B 4
#define C 64
#define H 256
#define W 256
#define CMID 16
#define CIN 73        // 64 + 9
#define HW (H*W)
#define NW (CIN*9*CMID)   // 10512 conv1 weights
#define XS_STRIDE 260     // offset kernel LDS row stride
#define XSR 258           // sim LDS row stride: [0]=left halo,[1..256]=x,[257]=right
#define PLN 258           // conv1 transposed row stride: 256 data + 2 halo slots

// ---------------------------------------------------------------------------
// w1 (CMID, CIN, 3, 3) -> wt[(ci*9+k)*CMID + co]
// ---------------------------------------------------------------------------
__global__ void transpose_w1_kernel(const float* __restrict__ w1, float* __restrict__ wt) {
    int tid = blockIdx.x * blockDim.x + threadIdx.x;
    if (tid >= NW) return;
    int co = tid & (CMID - 1);
    int rest = tid >> 4;          // ci*9 + k
    int ci = rest / 9;
    int k = rest - ci * 9;
    wt[tid] = w1[(co * CIN + ci) * 9 + k];
}

// 3x3 patch, row stride XSR. base = &xs[ch][tid]. (sim kernel)
__device__ __forceinline__ void read_patch9(const float* __restrict__ base, float v[9]) {
#pragma unroll
    for (int r = 0; r < 3; ++r) {
        v[r * 3 + 0] = base[r * XSR + 0];
        v[r * 3 + 1] = base[r * XSR + 1];
        v[r * 3 + 2] = base[r * XSR + 2];
    }
}

// ---------------------------------------------------------------------------
// Local cosine similarity. 1 px/thread, 4 ch per barrier, double-buffered.
// XCD-swizzled blocks. (unchanged — carries the swizzle win; conflicts ~0)
// ---------------------------------------------------------------------------
__global__ __launch_bounds__(256) void sim_kernel(const float* __restrict__ x,
                                                  float* __restrict__ sim) {
    __shared__ float xs[2][4][3 * XSR];   // 24768 B

    int bid = blockIdx.x;
    int sb = (bid & 7) * 128 + (bid >> 3);   // XCD-contiguous bands (1024 = 8*128)
    int b = sb >> 8;
    int y = sb & 255;
    int tid = threadIdx.x;

    const float* xb = x + (size_t)b * C * HW;

    bool rv[3];
    long off[3];
#pragma unroll
    for (int j = 0; j < 3; ++j) {
        int grow = y - 1 + j;
        rv[j] = (grow >= 0) && (grow < H);
        off[j] = (long)grow * W + tid;
    }

    if (tid < 48) {   // zero halo cols: 2 bufs x 4 ch x 3 rows x {0,257}
        int e = tid & 1;
        int r = (tid >> 1) % 3;
        int q = (tid >> 1) / 3;
        (&xs[0][0][0])[q * (3 * XSR) + r * XSR + (e ? 257 : 0)] = 0.f;
    }

    float dot[9], nsq[9];
    float csq = 0.f;
#pragma unroll
    for (int i = 0; i < 9; ++i) { dot[i] = nsq[i] = 0.f; }

    float p[12];
#pragma unroll
    for (int k = 0; k < 4; ++k)
#pragma unroll
        for (int j = 0; j < 3; ++j)
            p[k * 3 + j] = rv[j] ? xb[(size_t)k * HW + off[j]] : 0.f;

    int cur = 0;
#pragma unroll 1
    for (int cc = 0; cc < C; cc += 4) {
#pragma unroll
        for (int k = 0; k < 4; ++k)
#pragma unroll
            for (int j = 0; j < 3; ++j)
                xs[cur][k][j * XSR + 1 + tid] = p[k * 3 + j];
        __syncthreads();

        if (cc + 4 < C) {
#pragma unroll
            for (int k = 0; k < 4; ++k)
#pragma unroll
                for (int j = 0; j < 3; ++j)
                    p[k * 3 + j] = rv[j] ? xb[(size_t)(cc + 4 + k) * HW + off[j]] : 0.f;
        }

#pragma unroll
        for (int k = 0; k < 4; ++k) {
            float v[9];
            read_patch9(&xs[cur][k][tid], v);
            float cv = v[4];
            csq = fmaf(cv, cv, csq);
#pragma unroll
            for (int kk = 0; kk < 9; ++kk) {
                if (kk == 4) continue;
                dot[kk] = fmaf(cv, v[kk], dot[kk]);
                nsq[kk] = fmaf(v[kk], v[kk], nsq[kk]);
            }
        }
        cur ^= 1;
    }

    dot[4] = csq;
    nsq[4] = csq;
    float cn = sqrtf(csq) + 1e-8f;
    float* so = sim + (size_t)b * 9 * HW + (size_t)y * W + tid;
#pragma unroll
    for (int kk = 0; kk < 9; ++kk)
        so[(size_t)kk * HW] = dot[kk] / (cn * (sqrtf(nsq[kk]) + 1e-8f));
}

// ---------------------------------------------------------------------------
// Conv1 (73->16) + leaky.  co-split x 8px/thread, CONFLICT-FREE LDS:
//   Per (buf,ch,row), columns stored TRANSPOSED: col c at dword (c&3)*64+(c>>2),
//   halo slots: idx 256 = col -1 (0), idx 257 = col 256 (0).
//   -> staging = 4x ds_write_b32 stride-1 (2-way, free);
//   -> patch taps 4l+k = idx k*64+l, stride-1 b32 (merge to ds_read2_b32);
//   -> halo taps idx 191+l / l+1 with lane-edge fixup to 256/257 (stride-1).
//   Multi-dword DS ops are dword-phase-major: r4's b128 at 16B/lane stride was
//   an 8-way conflict every access (10.3M cyc measured) — this removes it.
//   Weights: VGPR double-buffered, one-channel-ahead forced-VMEM (unchanged).
// ---------------------------------------------------------------------------
__device__ __forceinline__ void conv1_co4(const float* __restrict__ pl, int l,
                                          int aL, int aR,
                                          const float4 wv[9], float4 acc[2][4]) {
    float v[4][6];
#pragma unroll
    for (int r = 0; r < 4; ++r) {
        const float* rp = pl + r * PLN;
        v[r][1] = rp[l];
        v[r][2] = rp[64 + l];
        v[r][3] = rp[128 + l];
        v[r][4] = rp[192 + l];
        v[r][0] = rp[aL];     // col 4l-1  (lane 0 -> slot 256 = 0)
        v[r][5] = rp[aR];     // col 4l+4  (lane 63 -> slot 257 = 0)
    }
#pragma unroll
    for (int kr = 0; kr < 3; ++kr)
#pragma unroll
        for (int kc = 0; kc < 3; ++kc) {
            float4 w = wv[kr * 3 + kc];
#pragma unroll
            for (int rr = 0; rr < 2; ++rr)
#pragma unroll
                for (int cc = 0; cc < 4; ++cc) {
                    float a = v[rr + kr][cc + kc];
                    acc[rr][cc].x = fmaf(a, w.x, acc[rr][cc].x);
                    acc[rr][cc].y = fmaf(a, w.y, acc[rr][cc].y);
                    acc[rr][cc].z = fmaf(a, w.z, acc[rr][cc].z);
                    acc[rr][cc].w = fmaf(a, w.w, acc[rr][cc].w);
                }
        }
}

__global__ __launch_bounds__(256) void conv1_kernel(const float* __restrict__ x,
                                                    const float* __restrict__ sim,
                                                    const float* __restrict__ wt,
                                                    const float* __restrict__ b1,
                                                    float* __restrict__ h) {
    __shared__ float xs[2][2][4 * PLN];   // 2 buf x 2 ch x 4 rows x 258 = 16512 B

    int tid = threadIdx.x;
    int l = tid & 63;
    int wid = tid >> 6;                       // wave: stages row wid, computes co 4*wid..+3
    int bid = blockIdx.x;
    int sb = (bid & 7) * 64 + (bid >> 3);     // XCD-contiguous bands (512 = 8*64)
    int b  = sb >> 7;
    int y0 = (sb & 127) << 1;

    // Opaque VGPR zero: keeps the wave-uniform weight loads on the VMEM path
    // (vmcnt), not the scalar path (lgkmcnt drain poison — r0/r1 lesson).
    int vz;
    asm volatile("v_mov_b32 %0, 0" : "=v"(vz));
    const float4* wq = (const float4*)wt + vz;

    const float* gx = x + (size_t)b * C * HW;
    const float* gs = sim + (size_t)b * 9 * HW;

    int grow = y0 - 1 + wid;                  // wave-uniform staging row
    bool rvw = (grow >= 0) && (grow < H);
    size_t goff = (size_t)grow * W + 4 * l;

    // per-lane halo tap indices (stride-1 across lanes; edges go to zero slots)
    int aL = (l == 0)  ? 256 : 191 + l;
    int aR = (l == 63) ? 257 : l + 1;

    if (tid < 32) {   // zero halo slots: 2 bufs x 2 ch x 4 rows x {256,257}
        int bu = tid >> 4, ch = (tid >> 3) & 1, r = (tid >> 1) & 3, e = tid & 1;
        xs[bu][ch][r * PLN + 256 + e] = 0.f;
    }

    float4 bias = ((const float4*)b1)[wid];
    float4 acc[2][4];
#pragma unroll
    for (int rr = 0; rr < 2; ++rr)
#pragma unroll
        for (int cc = 0; cc < 4; ++cc) acc[rr][cc] = bias;

    float4 wA[9], wB[9];
#pragma unroll
    for (int k = 0; k < 9; ++k) wA[k] = wq[k * 4 + wid];   // weights ch 0

    float4 p0 = make_float4(0.f, 0.f, 0.f, 0.f), p1 = p0;
    if (rvw) {
        p0 = *(const float4*)(gx + goff);
        p1 = *(const float4*)(gx + HW + goff);
    }

    int cur = 0;
#pragma unroll 1
    for (int cc2 = 0; cc2 < 72; cc2 += 2) {
        {   // transposed staging: 4x b32 stride-1 per channel
            float* d0 = &xs[cur][0][wid * PLN];
            d0[l] = p0.x; d0[64 + l] = p0.y; d0[128 + l] = p0.z; d0[192 + l] = p0.w;
            float* d1 = &xs[cur][1][wid * PLN];
            d1[l] = p1.x; d1[64 + l] = p1.y; d1[128 + l] = p1.z; d1[192 + l] = p1.w;
        }
        __syncthreads();

        // prefetch activations cc2+2, cc2+3 (uniform guards)
        {
            int ci = cc2 + 2;
            p0 = make_float4(0.f, 0.f, 0.f, 0.f);
            if (rvw)
                p0 = (ci < C) ? *(const float4*)(gx + (size_t)ci * HW + goff)
                              : *(const float4*)(gs + (size_t)(ci - C) * HW + goff);
            int cj = cc2 + 3;
            p1 = make_float4(0.f, 0.f, 0.f, 0.f);
            if (rvw && cj < CIN)
                p1 = (cj < C) ? *(const float4*)(gx + (size_t)cj * HW + goff)
                              : *(const float4*)(gs + (size_t)(cj - C) * HW + goff);
        }

        // prefetch weights ch cc2+1 (consumed one channel later)
#pragma unroll
        for (int k = 0; k < 9; ++k) wB[k] = wq[((cc2 + 1) * 9 + k) * 4 + wid];

        conv1_co4(&xs[cur][0][0], l, aL, aR, wA, acc);      // ch cc2

        // prefetch weights ch cc2+2
#pragma unroll
        for (int k = 0; k < 9; ++k) wA[k] = wq[((cc2 + 2) * 9 + k) * 4 + wid];

        conv1_co4(&xs[cur][1][0], l, aL, aR, wB, acc);      // ch cc2+1

        cur ^= 1;
    }

    // tail ci = 72 (activations in p0, weights in wA — both prefetched at cc2=70)
    {
        float* d0 = &xs[cur][0][wid * PLN];
        d0[l] = p0.x; d0[64 + l] = p0.y; d0[128 + l] = p0.z; d0[192 + l] = p0.w;
    }
    __syncthreads();
    conv1_co4(&xs[cur][0][0], l, aL, aR, wA, acc);

    // epilogue: leaky, transpose acc (col-vector-of-co -> co-planes), float4 stores
    float* ho = h + ((size_t)b * CMID + 4 * wid) * HW + (size_t)y0 * W + 4 * l;
#pragma unroll
    for (int rr = 0; rr < 2; ++rr)
#pragma unroll
        for (int j = 0; j < 4; ++j) {
            float4 o;
            o.x = ((const float*)&acc[rr][0])[j];
            o.y = ((const float*)&acc[rr][1])[j];
            o.z = ((const float*)&acc[rr][2])[j];
            o.w = ((const float*)&acc[rr][3])[j];
            o.x = o.x >= 0.f ? o.x : 0.2f * o.x;
            o.y = o.y >= 0.f ? o.y : 0.2f * o.y;
            o.z = o.z >= 0.f ? o.z : 0.2f * o.z;
            o.w = o.w >= 0.f ? o.w : 0.2f * o.w;
            *(float4*)(ho + (size_t)j * HW + (size_t)rr * W) = o;
        }
}

// ---------------------------------------------------------------------------
// Strip helpers for offset kernel (2-px/thread structure, stride 260).
// ---------------------------------------------------------------------------
__device__ __forceinline__ void read_patch_lds(const float* __restrict__ xsbuf,
                                               int rl, int px, float v[3][4]) {
    const float* pb = xsbuf + rl * XS_STRIDE + px;
#pragma unroll
    for (int r = 0; r < 3; ++r) {
        float2 p0 = *(const float2*)(pb + r * XS_STRIDE);
        float2 p1 = *(const float2*)(pb + r * XS_STRIDE + 2);
        v[r][0] = p0.x; v[r][1] = p0.y; v[r][2] = p1.x; v[r][3] = p1.y;
    }
}

// ---------------------------------------------------------------------------
// Conv2 (16->2) + tanh -> clamped sample coords. (unchanged)
// ---------------------------------------------------------------------------
__global__ __launch_bounds__(256) void offset_kernel(const float* __restrict__ h,
                                                     const float* __restrict__ w2,
                                                     const float* __restrict__ b2,
                                                     float2* __restrict__ off_buf) {
    __shared__ float lw2[CMID * 9 * 2];
    __shared__ float xs[2][4 * XS_STRIDE];

    int tid = threadIdx.x;
    for (int i = tid; i < CMID * 9 * 2; i += 256) {
        int co = i & 1;
        int rest = i >> 1;
        int ci = rest / 9;
        int kk = rest - ci * 9;
        lw2[i] = w2[(co * CMID + ci) * 9 + kk];
    }

    int bid = blockIdx.x;
    int sb = (bid & 7) * 64 + (bid >> 3);    // XCD-contiguous bands (512 = 8*64)
    int b  = sb >> 7;
    int y0 = (sb & 127) << 1;
    int srow = tid >> 6;
    int sx4  = (tid & 63) << 2;
    int rl = tid >> 7;
    int px = (tid & 127) << 1;
    int y  = y0 + rl;

    int grow = y0 - 1 + srow;
    bool gvalid = (grow >= 0) && (grow < H);
    const float* gh = h + (size_t)b * CMID * HW + (size_t)grow * W + sx4;

    if (tid < 16) {
        int bu = tid >> 3, r = (tid >> 1) & 3, e = (tid & 1) ? 257 : 0;
        xs[bu][r * XS_STRIDE + e] = 0.f;
    }

    float s0x = b2[0], s0y = b2[1], s1x = b2[0], s1y = b2[1];

    float4 r4 = make_float4(0.f, 0.f, 0.f, 0.f);
    if (gvalid) r4 = *(const float4*)gh;

    int cur = 0;
#pragma unroll 1
    for (int ci = 0; ci < CMID; ++ci) {
        float* dst = &xs[cur][srow * XS_STRIDE + 1 + sx4];
        dst[0] = r4.x; dst[1] = r4.y; dst[2] = r4.z; dst[3] = r4.w;
        __syncthreads();
        if (ci + 1 < CMID) {
            r4 = make_float4(0.f, 0.f, 0.f, 0.f);
            if (gvalid) r4 = *(const float4*)(gh + (size_t)(ci + 1) * HW);
        }
        float v[3][4];
        read_patch_lds(xs[cur], rl, px, v);
#pragma unroll
        for (int kr = 0; kr < 3; ++kr)
#pragma unroll
            for (int kc = 0; kc < 3; ++kc) {
                float2 wv = *(const float2*)(lw2 + (ci * 9 + kr * 3 + kc) * 2);
                s0x = fmaf(v[kr][kc],     wv.x, s0x);
                s0y = fmaf(v[kr][kc],     wv.y, s0y);
                s1x = fmaf(v[kr][kc + 1], wv.x, s1x);
                s1y = fmaf(v[kr][kc + 1], wv.y, s1y);
            }
        cur ^= 1;
    }

    float ix0 = (float)px       + 0.1f * tanhf(s0x) * (0.5f * (float)(W - 1));
    float iy0 = (float)y        + 0.1f * tanhf(s0y) * (0.5f * (float)(H - 1));
    float ix1 = (float)(px + 1) + 0.1f * tanhf(s1x) * (0.5f * (float)(W - 1));
    float iy1 = (float)y        + 0.1f * tanhf(s1y) * (0.5f * (float)(H - 1));
    ix0 = fminf(fmaxf(ix0, 0.f), (float)(W - 1));
    iy0 = fminf(fmaxf(iy0, 0.f), (float)(H - 1));
    ix1 = fminf(fmaxf(ix1, 0.f), (float)(W - 1));
    iy1 = fminf(fmaxf(iy1, 0.f), (float)(H - 1));

    float4* op = (float4*)(off_buf + (size_t)b * HW + (size_t)y * W + px);
    *op = make_float4(ix0, iy0, ix1, iy1);
}

// ---------------------------------------------------------------------------
// Bilinear border sample via LDS row cache. (unchanged)
// ---------------------------------------------------------------------------
#define SROWS 35
__global__ __launch_bounds__(256) void sample_kernel(const float* __restrict__ x,
                                                     const float2* __restrict__ off_buf,
                                                     float* __restrict__ out) {
    __shared__ float xs[SROWS * 256];    // 35840 B

    int bid = blockIdx.x;                        // 0..127 tiles
    int sb = (bid & 7) * 16 + (bid >> 3);        // XCD-contiguous 16-tile bands
    int b  = sb >> 5;
    int ty = sb & 31;
    int cg = blockIdx.y;                         // 0..15 channel groups (4 ch)
    int tid = threadIdx.x;                       // column

    int ybase = ty << 3;
    int lo = ybase - 13;

    int a00[8], a01[8], a10[8], a11[8];
    float wx[8], wy[8];
    const float2* ob2 = off_buf + (size_t)b * HW + (size_t)ybase * W + tid;
#pragma unroll
    for (int r = 0; r < 8; ++r) {
        float2 o = ob2[r * W];
        float xf = floorf(o.x), yf = floorf(o.y);
        wx[r] = o.x - xf; wy[r] = o.y - yf;
        int x0 = (int)xf, yy0 = (int)yf;
        int x1 = min(x0 + 1, W - 1), yy1 = min(yy0 + 1, H - 1);
        int r0 = (yy0 - lo) << 8, r1 = (yy1 - lo) << 8;
        a00[r] = r0 + x0; a01[r] = r0 + x1;
        a10[r] = r1 + x0; a11[r] = r1 + x1;
    }

    const float* xb = x + ((size_t)b * C + cg * 4) * HW;
    float* outb = out + ((size_t)b * C + cg * 4) * HW + (size_t)ybase * W + tid;

#pragma unroll 1
    for (int c = 0; c < 4; ++c) {
        __syncthreads();
        const float* src = xb + (size_t)c * HW;
        for (int j = tid; j < SROWS * 64; j += 256) {
            int row = j >> 6, x4 = (j & 63) << 2;
            int grw = min(max(lo + row, 0), H - 1);
            *(float4*)&xs[(row << 8) + x4] = *(const float4*)(src + (size_t)grw * W + x4);
        }
        __syncthreads();
        float* oc = outb + (size_t)c * HW;
#pragma unroll
        for (int r = 0; r < 8; ++r) {
            float v00 = xs[a00[r]], v01 = xs[a01[r]];
            float v10 = xs[a10[r]], v11 = xs[a11[r]];
            float top = fmaf(wx[r], v01 - v00, v00);
            float bot = fmaf(wx[r], v11 - v10, v10);
            oc[r * W] = fmaf(wy[r], bot - top, top);
        }
    }
}

// ---------------------------------------------------------------------------
extern "C" void kernel_launch(void* const* d_in, const int* in_sizes, int n_in,
                              void* d_out, int out_size, void* d_ws, size_t ws_size,
                              hipStream_t stream) {
    const float* x  = (const float*)d_in[0];
    const float* w1 = (const float*)d_in[1];
    const float* b1 = (const float*)d_in[2];
    const float* w2 = (const float*)d_in[3];
    const float* b2 = (const float*)d_in[4];
    float* out = (float*)d_out;

    float* ws  = (float*)d_ws;
    float* wt  = ws;                                         // 16384 floats
    float* sim = ws + 16384;                                 // B*9*HW
    float* h   = sim + (size_t)B * 9 * HW;                   // B*16*HW
    float2* off_buf = (float2*)(h + (size_t)B * CMID * HW);  // B*HW float2

    transpose_w1_kernel<<<(NW + 255) / 256, 256, 0, stream>>>(w1, wt);

    sim_kernel<<<B * H, 256, 0, stream>>>(x, sim);
    conv1_kernel<<<512, 256, 0, stream>>>(x, sim, wt, b1, h);
    offset_kernel<<<512, 256, 0, stream>>>(h, w2, b2, off_buf);
    sample_kernel<<<dim3(128, 16), 256, 0, stream>>>(x, off_buf, out);
}